// Round 8
// baseline (245.851 us; speedup 1.0000x reference)
//
#include <hip/hip_runtime.h>
#include <stdint.h>

#define NTOT 8192
#define BHALF 4096
#define DZ 512
#define DC 128
#define TEMPV 0.5f
#define FIXM 16.0f

typedef __attribute__((ext_vector_type(4))) float f32x4;
typedef __attribute__((ext_vector_type(4))) float floatx4;
typedef __attribute__((ext_vector_type(2))) unsigned long ulong2v;  // 16B = 2 fp8 frags
typedef __attribute__((ext_vector_type(4))) unsigned int uint4v;

#define MFMA8(a, b, c) __builtin_amdgcn_mfma_f32_16x16x32_fp8_fp8((long)(a), (long)(b), (c), 0, 0, 0)

__device__ __forceinline__ uint32_t pk4_e4m3(float f0, float f1, float f2, float f3) {
  int w = 0;
  w = __builtin_amdgcn_cvt_pk_fp8_f32(f0, f1, w, false);
  w = __builtin_amdgcn_cvt_pk_fp8_f32(f2, f3, w, true);
  return (uint32_t)w;
}

// ---------------- convert: fp32 -> fp8 e4m3, frag-pair-tiled; zeroes d_out ----------------
// 16B chunk ((ct*KP + cc)*64 + lane): bytes 0..7 = x[ct*16+ln][cc*64+lq*8..+8),
// bytes 8..15 = same +32 in k. A-frag layout (row-tile ct) == B-frag layout (col-tile ct).
__global__ void convert_kernel(const float* __restrict__ z_i, const float* __restrict__ z_j,
                               const float* __restrict__ c_i, const float* __restrict__ c_j,
                               uint8_t* __restrict__ zbT, uint8_t* __restrict__ cbT,
                               float* __restrict__ out) {
  const int ZC = NTOT * DZ / 16;   // 262144 chunks
  const int CC = NTOT * DC / 16;   // 65536
  int i = blockIdx.x * blockDim.x + threadIdx.x;
  if (i == 0) out[0] = 0.0f;               // zero the atomic loss target
  if (i >= ZC + CC) return;
  const float* src;
  uint8_t* dst;
  int k0;
  if (i < ZC) {
    int lane = i & 63, g = i >> 6;
    int ct = g >> 3, cc = g & 7;
    int ln = lane & 15, lq = lane >> 4;
    int row = ct * 16 + ln;
    k0 = cc * 64 + lq * 8;
    src = (row < BHALF) ? (z_i + (size_t)row * DZ) : (z_j + (size_t)(row - BHALF) * DZ);
    dst = zbT + (size_t)i * 16;
  } else {
    int i2 = i - ZC;
    int lane = i2 & 63, g = i2 >> 6;
    int ct = g >> 1, cc = g & 1;
    int ln = lane & 15, lq = lane >> 4;
    int row = ct * 16 + ln;
    k0 = cc * 64 + lq * 8;
    src = (row < BHALF) ? (c_i + (size_t)row * DC) : (c_j + (size_t)(row - BHALF) * DC);
    dst = cbT + (size_t)i2 * 16;
  }
  floatx4 a0 = *(const floatx4*)(src + k0);
  floatx4 a1 = *(const floatx4*)(src + k0 + 4);
  floatx4 b0 = *(const floatx4*)(src + k0 + 32);
  floatx4 b1 = *(const floatx4*)(src + k0 + 36);
  uint4v o;
  o.x = pk4_e4m3(a0[0], a0[1], a0[2], a0[3]);
  o.y = pk4_e4m3(a1[0], a1[1], a1[2], a1[3]);
  o.z = pk4_e4m3(b0[0], b0[1], b0[2], b0[3]);
  o.w = pk4_e4m3(b1[0], b1[1], b1[2], b1[3]);
  *(uint4v*)dst = o;
}

// stage col-tile ct into LDS (async, lane-ordered, 16B widths)
__device__ __forceinline__ void stage_tile(const uint8_t* __restrict__ zbT,
                                           const uint8_t* __restrict__ cbT,
                                           uint8_t* zS, uint8_t* cS,
                                           int ct, int w, int lane) {
#pragma unroll
  for (int j = 0; j < 2; ++j) {
    const int cc = w * 2 + j;
    const uint8_t* src = zbT + (((size_t)ct * 8 + cc) * 64 + lane) * 16;
    __builtin_amdgcn_global_load_lds((const __attribute__((address_space(1))) void*)src,
                                     (__attribute__((address_space(3))) void*)(zS + cc * 1024),
                                     16, 0, 0);
  }
  if (w < 2) {
    const uint8_t* src = cbT + (((size_t)ct * 2 + w) * 64 + lane) * 16;
    __builtin_amdgcn_global_load_lds((const __attribute__((address_space(1))) void*)src,
                                     (__attribute__((address_space(3))) void*)(cS + w * 1024),
                                     16, 0, 0);
  }
}

// ---------------- fused symmetric flash-lse: upper-triangle 128x128 blocks ----------------
// 1D grid of 2080 live blocks; triangular decode -> (rb, cb), rb <= cb.
// Each entry e=exp(s-16) contributes to row gr (register accum l_) AND col gc
// (register accum lc). Diag blocks mask gc<=gr; pair entries (blocks cb==rb+32,
// tile it=2w+s, lane ln==lq*4+r) masked to 0 (exact; pos added at finalize).
// NO atomics: plain stores of 128 row-partials -> RP[row][cb] and 128
// col-partials -> CP[col][rb]; finalize sums the valid triangular ranges.
__launch_bounds__(256, 4)
__global__ void fused_kernel(const uint8_t* __restrict__ zbT, const uint8_t* __restrict__ cbT,
                             float* __restrict__ RP, float* __restrict__ CP) {
  __shared__ __align__(16) uint8_t zS[2][8192];   // 2 x 8 KB
  __shared__ __align__(16) uint8_t cS[2][2048];   // 2 x 2 KB

  // triangular decode: t -> (rb, cb), rb <= cb, 2080 blocks
  const int t = blockIdx.x;
  const int u = 2079 - t;
  int k = (int)((__builtin_sqrtf(8.0f * (float)u + 1.0f) - 1.0f) * 0.5f);
  while ((k + 1) * (k + 2) / 2 <= u) ++k;
  while (k * (k + 1) / 2 > u) --k;
  const int j = u - k * (k + 1) / 2;
  const int rb = 63 - k;
  const int cb = 63 - j;
  const bool diagBlk = (rb == cb);
  const bool pairBlk = (cb == rb + 32);

  const int tid  = threadIdx.x;
  const int w    = tid >> 6;
  const int lane = tid & 63;
  const int lq   = lane >> 4;
  const int ln   = lane & 15;

  const int row_w = rb * 128 + w * 32;     // wave's 32 rows (2 sets of 16)
  const int rt0   = row_w >> 4;

  // A fragment pairs
  ulong2v a_z0[8], a_z1[8], a_c0[2], a_c1[2];
  {
    const uint8_t* p0 = zbT + ((size_t)rt0 * 8 * 64 + lane) * 16;
    const uint8_t* p1 = zbT + ((size_t)(rt0 + 1) * 8 * 64 + lane) * 16;
#pragma unroll
    for (int c = 0; c < 8; ++c) {
      a_z0[c] = *(const ulong2v*)(p0 + (size_t)c * 1024);
      a_z1[c] = *(const ulong2v*)(p1 + (size_t)c * 1024);
    }
    const uint8_t* q0 = cbT + ((size_t)rt0 * 2 * 64 + lane) * 16;
    const uint8_t* q1 = cbT + ((size_t)(rt0 + 1) * 2 * 64 + lane) * 16;
#pragma unroll
    for (int c = 0; c < 2; ++c) {
      a_c0[c] = *(const ulong2v*)(q0 + (size_t)c * 1024);
      a_c1[c] = *(const ulong2v*)(q1 + (size_t)c * 1024);
    }
  }

  float l_[8], lc[8];
#pragma unroll
  for (int r = 0; r < 8; ++r) { l_[r] = 0.0f; lc[r] = 0.0f; }

  const int ct_base = cb * 8;
  stage_tile(zbT, cbT, zS[0], cS[0], ct_base, w, lane);
  __syncthreads();

#pragma unroll
  for (int it = 0; it < 8; ++it) {
    const int cur = it & 1;
    if (it + 1 < 8)
      stage_tile(zbT, cbT, zS[cur ^ 1], cS[cur ^ 1], ct_base + it + 1, w, lane);

    const uint8_t* zb  = zS[cur];
    const uint8_t* cb_ = cS[cur];

    f32x4 ac0 = {0.f,0.f,0.f,0.f}, ac1 = {0.f,0.f,0.f,0.f};
#pragma unroll
    for (int c = 0; c < 2; ++c) {
      const ulong2v b = *(const ulong2v*)(cb_ + c * 1024 + lane * 16);
      ac0 = MFMA8(a_c0[c].x, b.x, ac0);
      ac0 = MFMA8(a_c0[c].y, b.y, ac0);
      ac1 = MFMA8(a_c1[c].x, b.x, ac1);
      ac1 = MFMA8(a_c1[c].y, b.y, ac1);
    }
    f32x4 az0 = {0.f,0.f,0.f,0.f}, az1 = {0.f,0.f,0.f,0.f};
#pragma unroll
    for (int c = 0; c < 8; ++c) {
      const ulong2v b = *(const ulong2v*)(zb + c * 1024 + lane * 16);
      az0 = MFMA8(a_z0[c].x, b.x, az0);
      az0 = MFMA8(a_z0[c].y, b.y, az0);
      az1 = MFMA8(a_z1[c].x, b.x, az1);
      az1 = MFMA8(a_z1[c].y, b.y, az1);
    }

    const int gc = cb * 128 + it * 16 + ln;
    float lcv = 0.0f;
#pragma unroll
    for (int s = 0; s < 2; ++s) {
      const f32x4 az = s ? az1 : az0;
      const f32x4 ac = s ? ac1 : ac0;
      const int grb = row_w + s * 16 + lq * 4;
      const bool pairTile = pairBlk && (it == w * 2 + s);
#pragma unroll
      for (int r = 0; r < 4; ++r) {
        float tv = fmaxf(ac[r], TEMPV);
        float sv = az[r] * __builtin_amdgcn_rcpf(tv);
        float e  = __expf(sv - FIXM);
        if (diagBlk && gc <= grb + r) e = 0.0f;        // diag + lower half
        if (pairTile && ln == lq * 4 + r) e = 0.0f;    // pair exclusion (exact)
        l_[s * 4 + r] += e;
        lcv += e;
      }
    }
    lc[it] += lcv;

    __syncthreads();   // protects cur buffer; prefetch drained here
  }

  // row partials -> RP[row][cb] (shuffle over the 16 column-lanes; offs 1..8 stay in quad group)
#pragma unroll
  for (int s = 0; s < 2; ++s) {
#pragma unroll
    for (int r = 0; r < 4; ++r) {
      float ll = l_[s * 4 + r];
#pragma unroll
      for (int off = 1; off < 16; off <<= 1) ll += __shfl_xor(ll, off);
      if (ln == 0) RP[(size_t)(row_w + s * 16 + lq * 4 + r) * 64 + cb] = ll;
    }
  }

  // col partials: reduce over lq, stash per-wave in reused LDS, cross-wave sum -> CP[col][rb]
  float* colbuf = (float*)&zS[0][0];   // safe: all zS reads done at last barrier
#pragma unroll
  for (int itt = 0; itt < 8; ++itt) {
    float v = lc[itt];
    v += __shfl_xor(v, 16);
    v += __shfl_xor(v, 32);
    if (lq == 0) colbuf[w * 128 + itt * 16 + ln] = v;
  }
  __syncthreads();
  if (tid < 128) {
    float s = colbuf[tid] + colbuf[128 + tid] + colbuf[256 + tid] + colbuf[384 + tid];
    CP[(size_t)(cb * 128 + tid) * 64 + rb] = s;
  }
}

// ---------------- finalize: exact fp32 pos + triangular partial merge + reduction ----------------
// 512 blocks x 1024 thr; one wave per row. Row r (block R=r>>7): negsum =
// sum_{cb>=R} RP[r][cb] + sum_{rb<=R} CP[r][rb]  (both reads coalesced 256B).
__global__ void finalize_kernel(const float* __restrict__ z_i, const float* __restrict__ z_j,
                                const float* __restrict__ RP, const float* __restrict__ CP,
                                float* __restrict__ out) {
  const int tid  = threadIdx.x;
  const int w    = tid >> 6;
  const int lane = tid & 63;
  const int row  = blockIdx.x * 16 + w;
  const int R    = row >> 7;

  // exact pos: fp32 dot(z[row], z[row^B]) * 2  (t forced to 0.5 at the pair)
  const float* zr = (row < BHALF) ? (z_i + (size_t)row * DZ) : (z_j + (size_t)(row - BHALF) * DZ);
  const float* zp = (row < BHALF) ? (z_j + (size_t)row * DZ) : (z_i + (size_t)(row - BHALF) * DZ);
  const int o = lane * 8;
  floatx4 a0 = *(const floatx4*)(zr + o), a1 = *(const floatx4*)(zr + o + 4);
  floatx4 b0 = *(const floatx4*)(zp + o), b1 = *(const floatx4*)(zp + o + 4);
  float d = a0[0]*b0[0] + a0[1]*b0[1] + a0[2]*b0[2] + a0[3]*b0[3]
          + a1[0]*b1[0] + a1[1]*b1[1] + a1[2]*b1[2] + a1[3]*b1[3];
#pragma unroll
  for (int off = 1; off < 64; off <<= 1) d += __shfl_xor(d, off);

  float v = 0.0f;
  if (lane >= R) v += RP[(size_t)row * 64 + lane];
  if (lane <= R) v += CP[(size_t)row * 64 + lane];
#pragma unroll
  for (int off = 1; off < 64; off <<= 1) v += __shfl_xor(v, off);

  __shared__ float red[16];
  if (lane == 0) {
    float pos  = 2.0f * d;
    float lneg = FIXM + __logf(v);
    float hi = fmaxf(lneg, pos), lo = fminf(lneg, pos);
    float lse = hi + __logf(1.0f + __expf(lo - hi));
    red[w] = lse - pos;
  }
  __syncthreads();
  if (tid == 0) {
    float s = 0.0f;
#pragma unroll
    for (int i = 0; i < 16; ++i) s += red[i];
    atomicAdd(out, s * (1.0f / NTOT));
  }
}

extern "C" void kernel_launch(void* const* d_in, const int* in_sizes, int n_in,
                              void* d_out, int out_size, void* d_ws, size_t ws_size,
                              hipStream_t stream) {
  const float* z_i = (const float*)d_in[0];
  const float* z_j = (const float*)d_in[1];
  const float* c_i = (const float*)d_in[2];
  const float* c_j = (const float*)d_in[3];

  uint8_t* zbT = (uint8_t*)d_ws;                        // 4 MB fp8 z (tiled)
  uint8_t* cbT = zbT + (size_t)NTOT * DZ;               // 1 MB fp8 c (tiled)
  float* RP = (float*)(cbT + (size_t)NTOT * DC);        // 8192*64 f32 = 2 MB
  float* CP = RP + (size_t)NTOT * 64;                   // 8192*64 f32 = 2 MB

  convert_kernel<<<1280, 256, 0, stream>>>(z_i, z_j, c_i, c_j, zbT, cbT, (float*)d_out);
  fused_kernel<<<2080, 256, 0, stream>>>(zbT, cbT, RP, CP);
  finalize_kernel<<<512, 1024, 0, stream>>>(z_i, z_j, RP, CP, (float*)d_out);
}

// Round 9
// 128.597 us; speedup vs baseline: 1.9118x; 1.9118x over previous
//
#include <hip/hip_runtime.h>
#include <stdint.h>

#define NTOT 8192
#define BHALF 4096
#define DZ 512
#define DC 128
#define TEMPV 0.5f
#define FIXM 16.0f

typedef __attribute__((ext_vector_type(4))) float f32x4;
typedef __attribute__((ext_vector_type(4))) float floatx4;
typedef __attribute__((ext_vector_type(2))) unsigned long ulong2v;  // 16B = 2 fp8 frags
typedef __attribute__((ext_vector_type(4))) unsigned int uint4v;

#define MFMA8(a, b, c) __builtin_amdgcn_mfma_f32_16x16x32_fp8_fp8((long)(a), (long)(b), (c), 0, 0, 0)

__device__ __forceinline__ uint32_t pk4_e4m3(float f0, float f1, float f2, float f3) {
  int w = 0;
  w = __builtin_amdgcn_cvt_pk_fp8_f32(f0, f1, w, false);
  w = __builtin_amdgcn_cvt_pk_fp8_f32(f2, f3, w, true);
  return (uint32_t)w;
}

// ---------------- convert: fp32 -> fp8 e4m3, frag-pair-tiled; zeroes d_out ----------------
// 16B chunk ((ct*KP + cc)*64 + lane): bytes 0..7 = x[ct*16+ln][cc*64+lq*8..+8),
// bytes 8..15 = same +32 in k. A-frag layout (row-tile ct) == B-frag layout (col-tile ct).
__global__ void convert_kernel(const float* __restrict__ z_i, const float* __restrict__ z_j,
                               const float* __restrict__ c_i, const float* __restrict__ c_j,
                               uint8_t* __restrict__ zbT, uint8_t* __restrict__ cbT,
                               float* __restrict__ out) {
  const int ZC = NTOT * DZ / 16;   // 262144 chunks
  const int CC = NTOT * DC / 16;   // 65536
  int i = blockIdx.x * blockDim.x + threadIdx.x;
  if (i == 0) out[0] = 0.0f;               // zero the atomic loss target
  if (i >= ZC + CC) return;
  const float* src;
  uint8_t* dst;
  int k0;
  if (i < ZC) {
    int lane = i & 63, g = i >> 6;
    int ct = g >> 3, cc = g & 7;
    int ln = lane & 15, lq = lane >> 4;
    int row = ct * 16 + ln;
    k0 = cc * 64 + lq * 8;
    src = (row < BHALF) ? (z_i + (size_t)row * DZ) : (z_j + (size_t)(row - BHALF) * DZ);
    dst = zbT + (size_t)i * 16;
  } else {
    int i2 = i - ZC;
    int lane = i2 & 63, g = i2 >> 6;
    int ct = g >> 1, cc = g & 1;
    int ln = lane & 15, lq = lane >> 4;
    int row = ct * 16 + ln;
    k0 = cc * 64 + lq * 8;
    src = (row < BHALF) ? (c_i + (size_t)row * DC) : (c_j + (size_t)(row - BHALF) * DC);
    dst = cbT + (size_t)i2 * 16;
  }
  floatx4 a0 = *(const floatx4*)(src + k0);
  floatx4 a1 = *(const floatx4*)(src + k0 + 4);
  floatx4 b0 = *(const floatx4*)(src + k0 + 32);
  floatx4 b1 = *(const floatx4*)(src + k0 + 36);
  uint4v o;
  o.x = pk4_e4m3(a0[0], a0[1], a0[2], a0[3]);
  o.y = pk4_e4m3(a1[0], a1[1], a1[2], a1[3]);
  o.z = pk4_e4m3(b0[0], b0[1], b0[2], b0[3]);
  o.w = pk4_e4m3(b1[0], b1[1], b1[2], b1[3]);
  *(uint4v*)dst = o;
}

// stage col-tile ct into LDS: 8 waves, wave w stages z chunk-group w; waves 0,1 stage c
__device__ __forceinline__ void stage_tile(const uint8_t* __restrict__ zbT,
                                           const uint8_t* __restrict__ cbT,
                                           uint8_t* zS, uint8_t* cS,
                                           int ct, int w, int lane) {
  const uint8_t* src = zbT + (((size_t)ct * 8 + w) * 64 + lane) * 16;
  __builtin_amdgcn_global_load_lds((const __attribute__((address_space(1))) void*)src,
                                   (__attribute__((address_space(3))) void*)(zS + w * 1024),
                                   16, 0, 0);
  if (w < 2) {
    const uint8_t* srcc = cbT + (((size_t)ct * 2 + w) * 64 + lane) * 16;
    __builtin_amdgcn_global_load_lds((const __attribute__((address_space(1))) void*)srcc,
                                     (__attribute__((address_space(3))) void*)(cS + w * 1024),
                                     16, 0, 0);
  }
}

// ---------------- fused symmetric flash-lse: upper-triangle 128x128 blocks ----------------
// 1D grid of 2080 live blocks (triangular decode, rb <= cb); 512 threads = 8 waves
// x 16 rows (ONE A-set/wave -> ~75 VGPR, safely under the 128 cap of
// __launch_bounds__(512,4); R8's 2-set variant spilled at the 128 cap: 264 MB scratch).
// Each entry e=exp(s-16) scatters to row accum l_ (registers) and col partials
// (shuffle -> colbuf LDS slot per (wave,tile,col), no extra registers).
// Diag blocks mask gc<=gr; pair entries (cb==rb+32, tile it==w, ln==lq*4+r) masked.
// NO atomics: RP[row][cb] / CP[col][rb] plain stores; finalize sums valid ranges.
__launch_bounds__(512, 4)
__global__ void fused_kernel(const uint8_t* __restrict__ zbT, const uint8_t* __restrict__ cbT,
                             float* __restrict__ RP, float* __restrict__ CP) {
  __shared__ __align__(16) uint8_t zS[2][8192];   // 2 x 8 KB
  __shared__ __align__(16) uint8_t cS[2][2048];   // 2 x 2 KB
  __shared__ float colbuf[8 * 128];               // 4 KB

  // triangular decode: t -> (rb, cb), rb <= cb, 2080 blocks
  const int t = blockIdx.x;
  const int u = 2079 - t;
  int k = (int)((__builtin_sqrtf(8.0f * (float)u + 1.0f) - 1.0f) * 0.5f);
  while ((k + 1) * (k + 2) / 2 <= u) ++k;
  while (k * (k + 1) / 2 > u) --k;
  const int j = u - k * (k + 1) / 2;
  const int rb = 63 - k;
  const int cb = 63 - j;
  const bool diagBlk = (rb == cb);
  const bool pairBlk = (cb == rb + 32);

  const int tid  = threadIdx.x;
  const int w    = tid >> 6;      // 0..7
  const int lane = tid & 63;
  const int lq   = lane >> 4;
  const int ln   = lane & 15;

  const int row_w = rb * 128 + w * 16;     // wave's 16 rows
  const int rt    = row_w >> 4;            // row-tile = rb*8 + w

  // A fragment pairs (one set: 32 + 8 VGPRs)
  ulong2v a_z[8], a_c[2];
  {
    const uint8_t* p = zbT + ((size_t)rt * 8 * 64 + lane) * 16;
#pragma unroll
    for (int c = 0; c < 8; ++c) a_z[c] = *(const ulong2v*)(p + (size_t)c * 1024);
    const uint8_t* q = cbT + ((size_t)rt * 2 * 64 + lane) * 16;
#pragma unroll
    for (int c = 0; c < 2; ++c) a_c[c] = *(const ulong2v*)(q + (size_t)c * 1024);
  }

  float l_[4] = {0.f, 0.f, 0.f, 0.f};

  const int ct_base = cb * 8;
  stage_tile(zbT, cbT, zS[0], cS[0], ct_base, w, lane);
  __syncthreads();

#pragma unroll
  for (int it = 0; it < 8; ++it) {
    const int cur = it & 1;
    if (it + 1 < 8)
      stage_tile(zbT, cbT, zS[cur ^ 1], cS[cur ^ 1], ct_base + it + 1, w, lane);

    float lcv = 0.0f;
    // wave-uniform skip: in diag blocks, tiles fully below this wave's rows
    if (!(diagBlk && it < w)) {
      const uint8_t* zb  = zS[cur];
      const uint8_t* cb_ = cS[cur];

      f32x4 ac = {0.f, 0.f, 0.f, 0.f};
#pragma unroll
      for (int c = 0; c < 2; ++c) {
        const ulong2v b = *(const ulong2v*)(cb_ + c * 1024 + lane * 16);
        ac = MFMA8(a_c[c].x, b.x, ac);
        ac = MFMA8(a_c[c].y, b.y, ac);
      }
      f32x4 az = {0.f, 0.f, 0.f, 0.f};
#pragma unroll
      for (int c = 0; c < 8; ++c) {
        const ulong2v b = *(const ulong2v*)(zb + c * 1024 + lane * 16);
        az = MFMA8(a_z[c].x, b.x, az);
        az = MFMA8(a_z[c].y, b.y, az);
      }

      const int gc  = cb * 128 + it * 16 + ln;
      const int grb = row_w + lq * 4;
      const bool pairTile = pairBlk && (it == w);
#pragma unroll
      for (int r = 0; r < 4; ++r) {
        float tv = fmaxf(ac[r], TEMPV);
        float sv = az[r] * __builtin_amdgcn_rcpf(tv);
        float e  = __expf(sv - FIXM);
        if (diagBlk && gc <= grb + r) e = 0.0f;        // diag + lower half
        if (pairTile && ln == lq * 4 + r) e = 0.0f;    // pair exclusion (exact)
        l_[r] += e;
        lcv += e;
      }
    }

    // col partial for this tile: reduce over lq, store (unique slot, pre-barrier)
    float v = lcv;
    v += __shfl_xor(v, 16);
    v += __shfl_xor(v, 32);
    if (lq == 0) colbuf[w * 128 + it * 16 + ln] = v;

    __syncthreads();   // protects cur buffer; drains prefetch; orders colbuf
  }

  // row partials -> RP[row][cb] (xor offs 1..8 stay within the quad group)
#pragma unroll
  for (int r = 0; r < 4; ++r) {
    float ll = l_[r];
#pragma unroll
    for (int off = 1; off < 16; off <<= 1) ll += __shfl_xor(ll, off);
    if (ln == 0) RP[(size_t)(row_w + lq * 4 + r) * 64 + cb] = ll;
  }

  // col partials: sum the 8 per-wave rows of colbuf -> CP[col][rb]
  if (tid < 128) {
    float s = 0.0f;
#pragma unroll
    for (int ww = 0; ww < 8; ++ww) s += colbuf[ww * 128 + tid];
    CP[(size_t)(cb * 128 + tid) * 64 + rb] = s;
  }
}

// ---------------- finalize: exact fp32 pos + triangular partial merge + reduction ----------------
// 512 blocks x 1024 thr; one wave per row. Row r (block R=r>>7): negsum =
// sum_{cb>=R} RP[r][cb] + sum_{rb<=R} CP[r][rb]  (both reads coalesced 256B).
__global__ void finalize_kernel(const float* __restrict__ z_i, const float* __restrict__ z_j,
                                const float* __restrict__ RP, const float* __restrict__ CP,
                                float* __restrict__ out) {
  const int tid  = threadIdx.x;
  const int w    = tid >> 6;
  const int lane = tid & 63;
  const int row  = blockIdx.x * 16 + w;
  const int R    = row >> 7;

  // exact pos: fp32 dot(z[row], z[row^B]) * 2  (t forced to 0.5 at the pair)
  const float* zr = (row < BHALF) ? (z_i + (size_t)row * DZ) : (z_j + (size_t)(row - BHALF) * DZ);
  const float* zp = (row < BHALF) ? (z_j + (size_t)row * DZ) : (z_i + (size_t)(row - BHALF) * DZ);
  const int o = lane * 8;
  floatx4 a0 = *(const floatx4*)(zr + o), a1 = *(const floatx4*)(zr + o + 4);
  floatx4 b0 = *(const floatx4*)(zp + o), b1 = *(const floatx4*)(zp + o + 4);
  float d = a0[0]*b0[0] + a0[1]*b0[1] + a0[2]*b0[2] + a0[3]*b0[3]
          + a1[0]*b1[0] + a1[1]*b1[1] + a1[2]*b1[2] + a1[3]*b1[3];
#pragma unroll
  for (int off = 1; off < 64; off <<= 1) d += __shfl_xor(d, off);

  float v = 0.0f;
  if (lane >= R) v += RP[(size_t)row * 64 + lane];
  if (lane <= R) v += CP[(size_t)row * 64 + lane];
#pragma unroll
  for (int off = 1; off < 64; off <<= 1) v += __shfl_xor(v, off);

  __shared__ float red[16];
  if (lane == 0) {
    float pos  = 2.0f * d;
    float lneg = FIXM + __logf(v);
    float hi = fmaxf(lneg, pos), lo = fminf(lneg, pos);
    float lse = hi + __logf(1.0f + __expf(lo - hi));
    red[w] = lse - pos;
  }
  __syncthreads();
  if (tid == 0) {
    float s = 0.0f;
#pragma unroll
    for (int i = 0; i < 16; ++i) s += red[i];
    atomicAdd(out, s * (1.0f / NTOT));
  }
}

extern "C" void kernel_launch(void* const* d_in, const int* in_sizes, int n_in,
                              void* d_out, int out_size, void* d_ws, size_t ws_size,
                              hipStream_t stream) {
  const float* z_i = (const float*)d_in[0];
  const float* z_j = (const float*)d_in[1];
  const float* c_i = (const float*)d_in[2];
  const float* c_j = (const float*)d_in[3];

  uint8_t* zbT = (uint8_t*)d_ws;                        // 4 MB fp8 z (tiled)
  uint8_t* cbT = zbT + (size_t)NTOT * DZ;               // 1 MB fp8 c (tiled)
  float* RP = (float*)(cbT + (size_t)NTOT * DC);        // 8192*64 f32 = 2 MB
  float* CP = RP + (size_t)NTOT * 64;                   // 8192*64 f32 = 2 MB

  convert_kernel<<<1280, 256, 0, stream>>>(z_i, z_j, c_i, c_j, zbT, cbT, (float*)d_out);
  fused_kernel<<<2080, 512, 0, stream>>>(zbT, cbT, RP, CP);
  finalize_kernel<<<512, 1024, 0, stream>>>(z_i, z_j, RP, CP, (float*)d_out);
}